// Round 9
// baseline (99734.576 us; speedup 1.0000x reference)
//
#include <hip/hip_runtime.h>
#include <math.h>

#define TMAX 200
#define NCL  8
#define CB   64

__device__ __forceinline__ float sig_(float x){ return 1.0f/(1.0f+expf(-x)); }

// 8 independent batch-clusters (64 batches each); no grid-wide sync ever.
// Cluster barrier: per-block slot store + leader-wave poll + go flag (monotonic epochs).
// ws: [0..4096) barrier ints (memset to 0 on stream each launch);
//     then xT[256][512], hT[1024][512], haT[2048][512]  (k-major, +4KB offset).
__device__ __forceinline__ void cl_sync(int* slots, int* go, int cl, int r, int nblk,
                                        int epoch, int tid, int l)
{
    __syncthreads();                    // all block lanes done with phase writes
    if (r == 0) {
        if (tid == 0) {
            __threadfence();            // release (L2 writeback covers whole cache)
            __hip_atomic_store(&slots[cl * CB + 0], epoch, __ATOMIC_RELEASE, __HIP_MEMORY_SCOPE_AGENT);
        }
        if (tid < 64) {                 // leader wave polls all slots in parallel
            for (;;) {
                int v = (l < nblk) ? __hip_atomic_load(&slots[cl * CB + l], __ATOMIC_ACQUIRE, __HIP_MEMORY_SCOPE_AGENT)
                                   : epoch;
                if (__all(v >= epoch)) break;
                __builtin_amdgcn_s_sleep(2);
            }
            if (tid == 0) {
                __hip_atomic_store(&go[cl], epoch, __ATOMIC_RELEASE, __HIP_MEMORY_SCOPE_AGENT);
                __threadfence();        // acquire side for this block
            }
        }
    } else {
        if (tid == 0) {
            __threadfence();            // release
            __hip_atomic_store(&slots[cl * CB + r], epoch, __ATOMIC_RELEASE, __HIP_MEMORY_SCOPE_AGENT);
            while (__hip_atomic_load(&go[cl], __ATOMIC_ACQUIRE, __HIP_MEMORY_SCOPE_AGENT) < epoch)
                __builtin_amdgcn_s_sleep(2);
            __threadfence();            // acquire (L2 invalidate covers whole cache)
        }
    }
    __syncthreads();
}

__global__ __launch_bounds__(256, 4)
void kfused(const int* __restrict__ lengths,
            const float* __restrict__ eps,
            const float* __restrict__ W_ih, const float* __restrict__ b_ih,
            const float* __restrict__ b_hh,
            const float* __restrict__ W1a, const float* __restrict__ b1a,
            const float* __restrict__ W1b, const float* __restrict__ b1b,
            const float* __restrict__ W2a, const float* __restrict__ b2a,
            const float* __restrict__ W2b, const float* __restrict__ b2b,
            float* __restrict__ out_p1, float* __restrict__ out_p2, float* __restrict__ out_h,
            int* __restrict__ bar, float* __restrict__ xT, float* __restrict__ hT,
            float* __restrict__ haT, int nblk)
{
    __shared__ float buf[2560];          // 10 KB: 4-wave reduce (2048) + pair (512)
    __shared__ int sbs[TMAX], soff[TMAX];

    const int tid = threadIdx.x;
    const int bid = blockIdx.x;
    const int wv  = tid >> 6;            // 0..3
    const int l   = tid & 63;            // lane = batch within cluster
    const int cl  = bid & 7;             // cluster id (XCD under round-robin)
    const int r   = bid >> 3;            // rank within cluster
    const int cb  = cl * CB;             // global batch base

    int* slots = bar;                    // [8][64]
    int* go    = bar + 512;              // [8]

    if (tid < TMAX) {
        int c = 0;
        for (int b = 0; b < 512; ++b) c += (lengths[b] > tid) ? 1 : 0;
        sbs[tid] = c;
    }
    __syncthreads();
    if (tid == 0) { int a = 0; for (int i = 0; i < TMAX; ++i) { soff[i] = a; a += sbs[i]; } }
    __syncthreads();

    int ep = 0;

    for (int t = 0; t < TMAX; ++t) {
        const int bsz = sbs[t], ofs = soff[t];

        // ============ phase A: gi = x@W_ih^T -> GRU -> h (j-sliced) ============
        for (int s = r; s < 64; s += nblk) {
            const int j0 = s * 16;
            float aR[4] = {0.f,0.f,0.f,0.f};
            float aZ[4] = {0.f,0.f,0.f,0.f};
            float aN[4] = {0.f,0.f,0.f,0.f};
            if (t > 0) {
                const float* __restrict__ xp = xT + cb + l;
                for (int k = 0; k < 256; k += 4) {
                    const float x0 = xp[(size_t)(k+0)*512];
                    const float x1 = xp[(size_t)(k+1)*512];
                    const float x2 = xp[(size_t)(k+2)*512];
                    const float x3 = xp[(size_t)(k+3)*512];
                    #pragma unroll
                    for (int q = 0; q < 4; ++q) {
                        const int j = j0 + wv*4 + q;
                        const float4 wr = *(const float4*)&W_ih[(size_t)j*256 + k];
                        const float4 wz = *(const float4*)&W_ih[(size_t)(1024+j)*256 + k];
                        const float4 wn = *(const float4*)&W_ih[(size_t)(2048+j)*256 + k];
                        aR[q] = fmaf(x3,wr.w,fmaf(x2,wr.z,fmaf(x1,wr.y,fmaf(x0,wr.x,aR[q]))));
                        aZ[q] = fmaf(x3,wz.w,fmaf(x2,wz.z,fmaf(x1,wz.y,fmaf(x0,wz.x,aZ[q]))));
                        aN[q] = fmaf(x3,wn.w,fmaf(x2,wn.z,fmaf(x1,wn.y,fmaf(x0,wn.x,aN[q]))));
                    }
                }
            }
            __syncthreads();             // buf free (prev slice / prev phase)
            #pragma unroll
            for (int q = 0; q < 4; ++q) {
                const int j = j0 + wv*4 + q;
                const float rr = sig_(aR[q] + b_ih[j] + b_hh[j]);
                const float zz = sig_(aZ[q] + b_ih[1024+j] + b_hh[1024+j]);
                const float nn = tanhf(aN[q] + b_ih[2048+j] + rr*b_hh[2048+j]);
                const float h = (1.f - zz)*nn;
                hT[(size_t)j*512 + cb + l] = h;
                buf[(wv*4+q)*64 + l] = h;
            }
            __syncthreads();
            {   // coalesced out_h rows (16 j per batch, float4 x4 threads)
                const int b = tid >> 2, jj = (tid & 3)*4;
                if (cb + b < bsz) {
                    float4 v = { buf[(jj+0)*64+b], buf[(jj+1)*64+b],
                                 buf[(jj+2)*64+b], buf[(jj+3)*64+b] };
                    *(float4*)&out_h[(size_t)(ofs + cb + b)*1024 + j0 + jj] = v;
                }
            }
        }
        cl_sync(slots, go, cl, r, nblk, ++ep, tid, l);

        // ============ phase B: ha = tanh(h @ Wa^T + ba) (n-sliced, full K) ============
        for (int s = r; s < 64; s += nblk) {
            const int n0 = s * 32;
            const float* __restrict__ Wa = (n0 < 1024) ? W1a : W2a;
            const float* __restrict__ ba = (n0 < 1024) ? b1a : b2a;
            const int nr0 = (n0 & 1023) + wv*8;
            float acc[8] = {0.f,0.f,0.f,0.f,0.f,0.f,0.f,0.f};
            const float* __restrict__ hp = hT + cb + l;
            for (int k = 0; k < 1024; k += 4) {
                const float h0 = hp[(size_t)(k+0)*512];
                const float h1 = hp[(size_t)(k+1)*512];
                const float h2 = hp[(size_t)(k+2)*512];
                const float h3 = hp[(size_t)(k+3)*512];
                #pragma unroll
                for (int c = 0; c < 8; ++c) {
                    const float4 w = *(const float4*)&Wa[(size_t)(nr0+c)*1024 + k];
                    acc[c] = fmaf(h3,w.w,fmaf(h2,w.z,fmaf(h1,w.y,fmaf(h0,w.x,acc[c]))));
                }
            }
            #pragma unroll
            for (int c = 0; c < 8; ++c)
                haT[(size_t)(n0 + wv*8 + c)*512 + cb + l] = tanhf(acc[c] + ba[nr0 + c]);
        }
        cl_sync(slots, go, cl, r, nblk, ++ep, tid, l);

        // ==== phase C: p = ha@Wb^T + bb (4+4 cols, wave K-split); scatter; x-fuse ====
        for (int s = r; s < 64; s += nblk) {
            const int c0 = s * 4;
            const int kb = wv * 256;
            float a1[4] = {0.f,0.f,0.f,0.f};
            float a2[4] = {0.f,0.f,0.f,0.f};
            const float* __restrict__ hp1 = haT + (size_t)kb*512 + cb + l;
            const float* __restrict__ hp2 = haT + (size_t)(1024+kb)*512 + cb + l;
            for (int k = 0; k < 256; k += 4) {
                const float u0 = hp1[(size_t)(k+0)*512];
                const float u1 = hp1[(size_t)(k+1)*512];
                const float u2 = hp1[(size_t)(k+2)*512];
                const float u3 = hp1[(size_t)(k+3)*512];
                const float v0 = hp2[(size_t)(k+0)*512];
                const float v1 = hp2[(size_t)(k+1)*512];
                const float v2 = hp2[(size_t)(k+2)*512];
                const float v3 = hp2[(size_t)(k+3)*512];
                #pragma unroll
                for (int c = 0; c < 4; ++c) {
                    const float4 w1 = *(const float4*)&W1b[(size_t)(c0+c)*1024 + kb + k];
                    const float4 w2 = *(const float4*)&W2b[(size_t)(c0+c)*1024 + kb + k];
                    a1[c] = fmaf(u3,w1.w,fmaf(u2,w1.z,fmaf(u1,w1.y,fmaf(u0,w1.x,a1[c]))));
                    a2[c] = fmaf(v3,w2.w,fmaf(v2,w2.z,fmaf(v1,w2.y,fmaf(v0,w2.x,a2[c]))));
                }
            }
            __syncthreads();             // buf free
            #pragma unroll
            for (int c = 0; c < 4; ++c) {
                buf[wv*512 + c*64 + l]     = a1[c];
                buf[wv*512 + (4+c)*64 + l] = a2[c];
            }
            __syncthreads();
            #pragma unroll
            for (int it = 0; it < 2; ++it) {   // 4-wave K reduce + bias
                const int idx = it*256 + tid;
                const int cc = idx >> 6, b = idx & 63;
                float p = buf[0*512 + cc*64 + b] + buf[1*512 + cc*64 + b]
                        + buf[2*512 + cc*64 + b] + buf[3*512 + cc*64 + b];
                p += (cc < 4) ? b1b[c0 + cc] : b2b[c0 + cc - 4];
                buf[2048 + cc*64 + b] = p;
            }
            __syncthreads();
            if (tid < 128) {             // scatter p rows (float4 per batch per family)
                const int fam = tid >> 6, b = tid & 63;
                if (cb + b < bsz) {
                    const int base = 2048 + fam*256;
                    float4 v = { buf[base + 0*64 + b], buf[base + 1*64 + b],
                                 buf[base + 2*64 + b], buf[base + 3*64 + b] };
                    float* __restrict__ dst = fam ? out_p2 : out_p1;
                    *(float4*)&dst[(size_t)(ofs + cb + b)*256 + c0] = v;
                }
            }
            {   // x_{t+1} = p1 + exp(0.5 p2) * eps[t]  (xT coalesced over b)
                const int c = tid >> 6, b = tid & 63;
                const float p1 = buf[2048 + c*64 + b];
                const float p2 = buf[2048 + 256 + c*64 + b];
                const float e = eps[(size_t)t*131072 + (size_t)(cb+b)*256 + c0 + c];
                xT[(size_t)(c0+c)*512 + cb + b] = fmaf(expf(0.5f*p2), e, p1);
            }
        }
        cl_sync(slots, go, cl, r, nblk, ++ep, tid, l);
    }
}

extern "C" void kernel_launch(void* const* d_in, const int* in_sizes, int n_in,
                              void* d_out, int out_size, void* d_ws, size_t ws_size,
                              hipStream_t stream)
{
    (void)in_sizes; (void)n_in; (void)ws_size;
    const int*   lengths = (const int*)  d_in[1];
    const float* eps     = (const float*)d_in[2];
    const float* W_ih    = (const float*)d_in[5];
    const float* b_ih    = (const float*)d_in[6];
    const float* b_hh    = (const float*)d_in[8];
    const float* W1a     = (const float*)d_in[9];
    const float* b1a     = (const float*)d_in[10];
    const float* W1b     = (const float*)d_in[11];
    const float* b1b     = (const float*)d_in[12];
    const float* W2a     = (const float*)d_in[13];
    const float* b2a     = (const float*)d_in[14];
    const float* W2b     = (const float*)d_in[15];
    const float* b2b     = (const float*)d_in[16];

    float* out = (float*)d_out;
    const size_t N = (size_t)out_size / 1536;
    float* out_p1 = out;
    float* out_p2 = out + N * 256;
    float* out_h  = out + N * 512;

    int*   bar = (int*)d_ws;                          // 4 KB barrier region
    float* xT  = (float*)((char*)d_ws + 4096);        // [256][512]
    float* hT  = xT + 131072;                         // [1024][512]
    float* haT = hT + 524288;                         // [2048][512]  total ~6.8 MB

    // reset barrier epochs (graph-capturable, deterministic per replay)
    hipMemsetAsync(d_ws, 0, 4096, stream);

    // co-residency-sized grid (multiple of 8); homebrew barrier needs residency,
    // cooperative launch guarantees it.
    int dev = 0;
    (void)hipGetDevice(&dev);
    int ncu = 0;
    if (hipDeviceGetAttribute(&ncu, hipDeviceAttributeMultiprocessorCount, dev) != hipSuccess || ncu <= 0)
        ncu = 256;
    int maxB = 0;
    if (hipOccupancyMaxActiveBlocksPerMultiprocessor(&maxB, (const void*)kfused, 256, 0) != hipSuccess || maxB <= 0)
        maxB = 1;
    long cap = (long)maxB * (long)ncu;
    int grd = (cap < 512) ? (int)(cap & ~7L) : 512;
    if (grd < 8) grd = 8;

    for (;;) {
        int nblk = grd >> 3;
        void* args[] = {
            (void*)&lengths, (void*)&eps, (void*)&W_ih, (void*)&b_ih, (void*)&b_hh,
            (void*)&W1a, (void*)&b1a, (void*)&W1b, (void*)&b1b,
            (void*)&W2a, (void*)&b2a, (void*)&W2b, (void*)&b2b,
            (void*)&out_p1, (void*)&out_p2, (void*)&out_h,
            (void*)&bar, (void*)&xT, (void*)&hT, (void*)&haT, (void*)&nblk
        };
        hipError_t err = hipLaunchCooperativeKernel((void*)kfused, dim3(grd), dim3(256), args, 0, stream);
        if (err == hipSuccess || grd <= 8) break;
        grd >>= 1;                      // halve and retry (stays multiple of 8)
    }
}

// Round 10
// 42380.319 us; speedup vs baseline: 2.3533x; 2.3533x over previous
//
#include <hip/hip_runtime.h>
#include <math.h>

#define TMAX 200
#define CB   64

__device__ __forceinline__ float sig_(float x){ return 1.0f/(1.0f+expf(-x)); }

// Light cluster barrier: one atomicAdd + go flag, single poller per block.
__device__ __forceinline__ void cl_sync(int* cnt, int* go, int nblk, int ep, int tid)
{
    __syncthreads();
    if (tid == 0) {
        __threadfence();
        int old = __hip_atomic_fetch_add(cnt, 1, __ATOMIC_ACQ_REL, __HIP_MEMORY_SCOPE_AGENT);
        if (old == nblk - 1) {
            __hip_atomic_store(cnt, 0, __ATOMIC_RELAXED, __HIP_MEMORY_SCOPE_AGENT);
            __hip_atomic_store(go, ep, __ATOMIC_RELEASE, __HIP_MEMORY_SCOPE_AGENT);
        } else {
            while (__hip_atomic_load(go, __ATOMIC_ACQUIRE, __HIP_MEMORY_SCOPE_AGENT) < ep)
                __builtin_amdgcn_s_sleep(16);
        }
        __threadfence();
    }
    __syncthreads();
}

// LDS float offsets: XS[2] @0/2432 ([32][76]); WS[2] @4864/8064 ([32][100] A, [32][68] B, [32][12] C)
// A aux: gi [96][68] @0 ; h bounce [32][68] @6528
// C aux: red [64][68] @0 ; e_lds [64][12] @4864 ; pbounce [64][20] @5700
#define LDSF 11264

__global__ __launch_bounds__(256, 2)
void kfused(const int* __restrict__ lengths,
            const float* __restrict__ eps,
            const float* __restrict__ W_ih, const float* __restrict__ b_ih,
            const float* __restrict__ b_hh,
            const float* __restrict__ W1a, const float* __restrict__ b1a,
            const float* __restrict__ W1b, const float* __restrict__ b1b,
            const float* __restrict__ W2a, const float* __restrict__ b2a,
            const float* __restrict__ W2b, const float* __restrict__ b2b,
            float* __restrict__ out_p1, float* __restrict__ out_p2, float* __restrict__ out_h,
            int* __restrict__ bar, float* __restrict__ xT, float* __restrict__ hT,
            float* __restrict__ haT, int nblk)
{
    __shared__ float lds[LDSF];
    __shared__ int sbs[TMAX], soff[TMAX];

    const int tid = threadIdx.x;
    const int bid = blockIdx.x;
    const int cl  = bid & 7;             // cluster -> XCD (round-robin heuristic)
    const int r   = bid >> 3;            // rank in cluster
    const int cb  = cl * CB;

    int* cnt = &bar[cl * 64];
    int* go  = &bar[cl * 64 + 16];

    if (tid < TMAX) {
        int c = 0;
        for (int b = 0; b < 512; ++b) c += (lengths[b] > tid) ? 1 : 0;
        sbs[tid] = c;
    }
    __syncthreads();
    if (tid == 0) { int a = 0; for (int i = 0; i < TMAX; ++i) { soff[i] = a; a += sbs[i]; } }
    __syncthreads();

    for (int t = 0; t < TMAX; ++t) {
        const int bsz = sbs[t], ofs = soff[t];

        // ================= phase A: gi = x @ W_ih^T -> GRU -> h =================
        for (int s = r; s < 32; s += nblk) {
            const int j0 = s * 32;
            const int tx = tid & 15, ty = tid >> 4;
            float acc[4][6];
            #pragma unroll
            for (int i = 0; i < 4; ++i)
                #pragma unroll
                for (int q = 0; q < 6; ++q) acc[i][q] = 0.f;

            if (t > 0) {
                const int sk = tid >> 3, sb = (tid & 7) * 8;
                const int wj = tid >> 3, wk = (tid & 7) * 4;
                float4 px0, px1, pw0, pw1, pw2;
                px0 = *(const float4*)&xT[(size_t)sk * 512 + cb + sb];
                px1 = *(const float4*)&xT[(size_t)sk * 512 + cb + sb + 4];
                pw0 = *(const float4*)&W_ih[(size_t)(j0 + wj) * 256 + wk];
                pw1 = *(const float4*)&W_ih[(size_t)(1024 + j0 + wj) * 256 + wk];
                pw2 = *(const float4*)&W_ih[(size_t)(2048 + j0 + wj) * 256 + wk];
                {
                    float* xs = lds; float* ws = lds + 4864;
                    *(float4*)&xs[sk * 76 + sb] = px0;
                    *(float4*)&xs[sk * 76 + sb + 4] = px1;
                    const float* a0 = &pw0.x; const float* a1 = &pw1.x; const float* a2 = &pw2.x;
                    #pragma unroll
                    for (int m = 0; m < 4; ++m) {
                        ws[(wk+m)*100 + wj]      = a0[m];
                        ws[(wk+m)*100 + 32 + wj] = a1[m];
                        ws[(wk+m)*100 + 64 + wj] = a2[m];
                    }
                }
                for (int kc = 0; kc < 8; ++kc) {
                    __syncthreads();
                    const int cur = kc & 1;
                    if (kc < 7) {
                        const int kb = (kc + 1) * 32;
                        px0 = *(const float4*)&xT[(size_t)(kb + sk) * 512 + cb + sb];
                        px1 = *(const float4*)&xT[(size_t)(kb + sk) * 512 + cb + sb + 4];
                        pw0 = *(const float4*)&W_ih[(size_t)(j0 + wj) * 256 + kb + wk];
                        pw1 = *(const float4*)&W_ih[(size_t)(1024 + j0 + wj) * 256 + kb + wk];
                        pw2 = *(const float4*)&W_ih[(size_t)(2048 + j0 + wj) * 256 + kb + wk];
                    }
                    const float* xs = lds + cur * 2432;
                    const float* ws = lds + 4864 + cur * 3200;
                    #pragma unroll 4
                    for (int kk = 0; kk < 32; ++kk) {
                        const float4 a4 = *(const float4*)&xs[kk * 76 + ty * 4];
                        float w[6];
                        #pragma unroll
                        for (int q = 0; q < 6; ++q) w[q] = ws[kk * 100 + tx * 6 + q];
                        const float av[4] = {a4.x, a4.y, a4.z, a4.w};
                        #pragma unroll
                        for (int i = 0; i < 4; ++i)
                            #pragma unroll
                            for (int q = 0; q < 6; ++q)
                                acc[i][q] = fmaf(av[i], w[q], acc[i][q]);
                    }
                    if (kc < 7) {
                        float* xs2 = lds + (cur ^ 1) * 2432;
                        float* ws2 = lds + 4864 + (cur ^ 1) * 3200;
                        *(float4*)&xs2[sk * 76 + sb] = px0;
                        *(float4*)&xs2[sk * 76 + sb + 4] = px1;
                        const float* a0 = &pw0.x; const float* a1 = &pw1.x; const float* a2 = &pw2.x;
                        #pragma unroll
                        for (int m = 0; m < 4; ++m) {
                            ws2[(wk+m)*100 + wj]      = a0[m];
                            ws2[(wk+m)*100 + 32 + wj] = a1[m];
                            ws2[(wk+m)*100 + 64 + wj] = a2[m];
                        }
                    }
                }
            }
            __syncthreads();
            // gi -> lds[96][68]
            #pragma unroll
            for (int q = 0; q < 6; ++q) {
                const int n = tx * 6 + q;
                #pragma unroll
                for (int i = 0; i < 4; ++i) lds[n * 68 + ty * 4 + i] = acc[i][q];
            }
            __syncthreads();
            // GRU + hT write + h bounce
            {
                const int jr = tid & 31, bq = (tid >> 5) * 8;
                const int j = j0 + jr;
                const float brr = b_ih[j] + b_hh[j];
                const float bzz = b_ih[1024 + j] + b_hh[1024 + j];
                const float bnn = b_ih[2048 + j];
                const float gnn = b_hh[2048 + j];
                float hv[8];
                #pragma unroll
                for (int i = 0; i < 8; ++i) {
                    const int b = bq + i;
                    const float rr = sig_(lds[jr * 68 + b] + brr);
                    const float zz = sig_(lds[(32 + jr) * 68 + b] + bzz);
                    const float nn = tanhf(lds[(64 + jr) * 68 + b] + bnn + rr * gnn);
                    hv[i] = (1.f - zz) * nn;
                    hT[(size_t)j * 512 + cb + b] = hv[i];
                }
                #pragma unroll
                for (int i = 0; i < 8; ++i) lds[6528 + jr * 68 + bq + i] = hv[i];
            }
            __syncthreads();
            {
                const int b = tid >> 2, q = tid & 3;
                if (cb + b < bsz) {
                    float4 v0, v1;
                    v0.x = lds[6528 + (q*8+0)*68 + b]; v0.y = lds[6528 + (q*8+1)*68 + b];
                    v0.z = lds[6528 + (q*8+2)*68 + b]; v0.w = lds[6528 + (q*8+3)*68 + b];
                    v1.x = lds[6528 + (q*8+4)*68 + b]; v1.y = lds[6528 + (q*8+5)*68 + b];
                    v1.z = lds[6528 + (q*8+6)*68 + b]; v1.w = lds[6528 + (q*8+7)*68 + b];
                    *(float4*)&out_h[(size_t)(ofs + cb + b) * 1024 + j0 + q * 8] = v0;
                    *(float4*)&out_h[(size_t)(ofs + cb + b) * 1024 + j0 + q * 8 + 4] = v1;
                }
            }
            __syncthreads();
        }
        cl_sync(cnt, go, nblk, t * 3 + 1, tid);

        // ================= phase B: ha = tanh(h @ Wa^T + ba) =================
        for (int s = r; s < 32; s += nblk) {
            const int n0 = s * 64;
            const float* __restrict__ Wa = (n0 < 1024) ? W1a : W2a;
            const float* __restrict__ ba = (n0 < 1024) ? b1a : b2a;
            const int nr0 = n0 & 1023;
            const int tx = tid & 15, ty = tid >> 4;
            const int sk = tid >> 3, sb = (tid & 7) * 8;
            const int wn = tid >> 2, wk0 = (tid & 3) * 8;
            float acc[4][4];
            #pragma unroll
            for (int i = 0; i < 4; ++i)
                #pragma unroll
                for (int j = 0; j < 4; ++j) acc[i][j] = 0.f;

            float4 px0, px1, pw0, pw1;
            px0 = *(const float4*)&hT[(size_t)sk * 512 + cb + sb];
            px1 = *(const float4*)&hT[(size_t)sk * 512 + cb + sb + 4];
            pw0 = *(const float4*)&Wa[(size_t)(nr0 + wn) * 1024 + wk0];
            pw1 = *(const float4*)&Wa[(size_t)(nr0 + wn) * 1024 + wk0 + 4];
            {
                float* xs = lds; float* ws = lds + 4864;
                *(float4*)&xs[sk * 76 + sb] = px0;
                *(float4*)&xs[sk * 76 + sb + 4] = px1;
                const float* a0 = &pw0.x; const float* a1 = &pw1.x;
                #pragma unroll
                for (int m = 0; m < 4; ++m) {
                    ws[(wk0+m)*68 + wn]   = a0[m];
                    ws[(wk0+4+m)*68 + wn] = a1[m];
                }
            }
            for (int kc = 0; kc < 32; ++kc) {
                __syncthreads();
                const int cur = kc & 1;
                if (kc < 31) {
                    const int kb = (kc + 1) * 32;
                    px0 = *(const float4*)&hT[(size_t)(kb + sk) * 512 + cb + sb];
                    px1 = *(const float4*)&hT[(size_t)(kb + sk) * 512 + cb + sb + 4];
                    pw0 = *(const float4*)&Wa[(size_t)(nr0 + wn) * 1024 + kb + wk0];
                    pw1 = *(const float4*)&Wa[(size_t)(nr0 + wn) * 1024 + kb + wk0 + 4];
                }
                const float* xs = lds + cur * 2432;
                const float* ws = lds + 4864 + cur * 3200;
                #pragma unroll 4
                for (int kk = 0; kk < 32; ++kk) {
                    const float4 a4 = *(const float4*)&xs[kk * 76 + ty * 4];
                    const float4 w4 = *(const float4*)&ws[kk * 68 + tx * 4];
                    const float av[4] = {a4.x, a4.y, a4.z, a4.w};
                    const float wv[4] = {w4.x, w4.y, w4.z, w4.w};
                    #pragma unroll
                    for (int i = 0; i < 4; ++i)
                        #pragma unroll
                        for (int j = 0; j < 4; ++j)
                            acc[i][j] = fmaf(av[i], wv[j], acc[i][j]);
                }
                if (kc < 31) {
                    float* xs2 = lds + (cur ^ 1) * 2432;
                    float* ws2 = lds + 4864 + (cur ^ 1) * 3200;
                    *(float4*)&xs2[sk * 76 + sb] = px0;
                    *(float4*)&xs2[sk * 76 + sb + 4] = px1;
                    const float* a0 = &pw0.x; const float* a1 = &pw1.x;
                    #pragma unroll
                    for (int m = 0; m < 4; ++m) {
                        ws2[(wk0+m)*68 + wn]   = a0[m];
                        ws2[(wk0+4+m)*68 + wn] = a1[m];
                    }
                }
            }
            #pragma unroll
            for (int j = 0; j < 4; ++j) {
                const float bias = ba[nr0 + tx * 4 + j];
                float4 hv;
                hv.x = tanhf(acc[0][j] + bias);
                hv.y = tanhf(acc[1][j] + bias);
                hv.z = tanhf(acc[2][j] + bias);
                hv.w = tanhf(acc[3][j] + bias);
                *(float4*)&haT[(size_t)(n0 + tx * 4 + j) * 512 + cb + ty * 4] = hv;
            }
            __syncthreads();
        }
        cl_sync(cnt, go, nblk, t * 3 + 2, tid);

        // ===== phase C: p1/p2 = ha @ Wb^T + bb (8 cols, both fams); scatter; x-fuse =====
        for (int s = r; s < 32; s += nblk) {
            const int c0 = s * 8;
            const int g = tid >> 6, b = tid & 63;
            const int sk = tid >> 3, sb = (tid & 7) * 8;
            float accf[2][8];
            #pragma unroll
            for (int f = 0; f < 2; ++f)
                #pragma unroll
                for (int c = 0; c < 8; ++c) accf[f][c] = 0.f;

            #pragma unroll 1
            for (int f = 0; f < 2; ++f) {
                const float* __restrict__ Wb = f ? W2b : W1b;
                const float* __restrict__ hap = haT + (size_t)f * 1024 * 512;
                float4 px0, px1, pwv;
                px0 = *(const float4*)&hap[(size_t)sk * 512 + cb + sb];
                px1 = *(const float4*)&hap[(size_t)sk * 512 + cb + sb + 4];
                const int cw = (tid & 63) >> 3, ck = (tid & 7) * 4;
                if (tid < 64) pwv = *(const float4*)&Wb[(size_t)(c0 + cw) * 1024 + ck];
                {
                    float* xs = lds; float* ws = lds + 4864;
                    *(float4*)&xs[sk * 76 + sb] = px0;
                    *(float4*)&xs[sk * 76 + sb + 4] = px1;
                    if (tid < 64) {
                        const float* a0 = &pwv.x;
                        #pragma unroll
                        for (int m = 0; m < 4; ++m) ws[(ck+m)*12 + cw] = a0[m];
                    }
                }
                for (int kc = 0; kc < 32; ++kc) {
                    __syncthreads();
                    const int cur = kc & 1;
                    if (kc < 31) {
                        const int kb = (kc + 1) * 32;
                        px0 = *(const float4*)&hap[(size_t)(kb + sk) * 512 + cb + sb];
                        px1 = *(const float4*)&hap[(size_t)(kb + sk) * 512 + cb + sb + 4];
                        if (tid < 64) pwv = *(const float4*)&Wb[(size_t)(c0 + cw) * 1024 + kb + ck];
                    }
                    const float* xs = lds + cur * 2432;
                    const float* ws = lds + 4864 + cur * 3200;
                    #pragma unroll
                    for (int k8 = 0; k8 < 8; ++k8) {
                        const int kk = g * 8 + k8;
                        const float a = xs[kk * 76 + b];
                        const float4 wlo = *(const float4*)&ws[kk * 12];
                        const float4 whi = *(const float4*)&ws[kk * 12 + 4];
                        accf[f][0] = fmaf(a, wlo.x, accf[f][0]);
                        accf[f][1] = fmaf(a, wlo.y, accf[f][1]);
                        accf[f][2] = fmaf(a, wlo.z, accf[f][2]);
                        accf[f][3] = fmaf(a, wlo.w, accf[f][3]);
                        accf[f][4] = fmaf(a, whi.x, accf[f][4]);
                        accf[f][5] = fmaf(a, whi.y, accf[f][5]);
                        accf[f][6] = fmaf(a, whi.z, accf[f][6]);
                        accf[f][7] = fmaf(a, whi.w, accf[f][7]);
                    }
                    if (kc < 31) {
                        float* xs2 = lds + (cur ^ 1) * 2432;
                        float* ws2 = lds + 4864 + (cur ^ 1) * 3200;
                        *(float4*)&xs2[sk * 76 + sb] = px0;
                        *(float4*)&xs2[sk * 76 + sb + 4] = px1;
                        if (tid < 64) {
                            const float* a0 = &pwv.x;
                            #pragma unroll
                            for (int m = 0; m < 4; ++m) ws2[(ck+m)*12 + cw] = a0[m];
                        }
                    }
                }
            }
            __syncthreads();
            // red[(f*4+g)*8+c][68] + e_lds
            #pragma unroll
            for (int c = 0; c < 8; ++c) {
                lds[((0 * 4 + g) * 8 + c) * 68 + b] = accf[0][c];
                lds[((1 * 4 + g) * 8 + c) * 68 + b] = accf[1][c];
            }
            {
                const int b2 = tid >> 2, q = tid & 3;
                const float2 e = *(const float2*)&eps[(size_t)t * 131072 + (size_t)(cb + b2) * 256 + c0 + q * 2];
                lds[4864 + b2 * 12 + q * 2]     = e.x;
                lds[4864 + b2 * 12 + q * 2 + 1] = e.y;
            }
            __syncthreads();
            {
                const int cp = tid >> 6;
                #pragma unroll
                for (int e = 0; e < 2; ++e) {
                    const int cc = cp * 2 + e;
                    float p1 = b1b[c0 + cc], p2 = b2b[c0 + cc];
                    #pragma unroll
                    for (int gg = 0; gg < 4; ++gg) {
                        p1 += lds[((0 * 4 + gg) * 8 + cc) * 68 + b];
                        p2 += lds[((1 * 4 + gg) * 8 + cc) * 68 + b];
                    }
                    const float x = fmaf(expf(0.5f * p2), lds[4864 + b * 12 + cc], p1);
                    xT[(size_t)(c0 + cc) * 512 + cb + b] = x;
                    lds[5700 + b * 20 + cc]     = p1;
                    lds[5700 + b * 20 + 8 + cc] = p2;
                }
            }
            __syncthreads();
            {
                const int bb2 = tid >> 2, q = tid & 3;
                if (cb + bb2 < bsz) {
                    if (q < 2) {
                        *(float4*)&out_p1[(size_t)(ofs + cb + bb2) * 256 + c0 + q * 4] =
                            *(const float4*)&lds[5700 + bb2 * 20 + q * 4];
                    } else {
                        *(float4*)&out_p2[(size_t)(ofs + cb + bb2) * 256 + c0 + (q - 2) * 4] =
                            *(const float4*)&lds[5700 + bb2 * 20 + 8 + (q - 2) * 4];
                    }
                }
            }
            __syncthreads();
        }
        cl_sync(cnt, go, nblk, t * 3 + 3, tid);
    }
}

extern "C" void kernel_launch(void* const* d_in, const int* in_sizes, int n_in,
                              void* d_out, int out_size, void* d_ws, size_t ws_size,
                              hipStream_t stream)
{
    (void)in_sizes; (void)n_in; (void)ws_size;
    const int*   lengths = (const int*)  d_in[1];
    const float* eps     = (const float*)d_in[2];
    const float* W_ih    = (const float*)d_in[5];
    const float* b_ih    = (const float*)d_in[6];
    const float* b_hh    = (const float*)d_in[8];
    const float* W1a     = (const float*)d_in[9];
    const float* b1a     = (const float*)d_in[10];
    const float* W1b     = (const float*)d_in[11];
    const float* b1b     = (const float*)d_in[12];
    const float* W2a     = (const float*)d_in[13];
    const float* b2a     = (const float*)d_in[14];
    const float* W2b     = (const float*)d_in[15];
    const float* b2b     = (const float*)d_in[16];

    float* out = (float*)d_out;
    const size_t N = (size_t)out_size / 1536;
    float* out_p1 = out;
    float* out_p2 = out + N * 256;
    float* out_h  = out + N * 512;

    int*   bar = (int*)d_ws;                      // 4 KB barrier region
    float* xT  = (float*)((char*)d_ws + 4096);    // [256][512]
    float* hT  = xT + 131072;                     // [1024][512]
    float* haT = hT + 524288;                     // [2048][512]  (~6.8 MB total)

    hipMemsetAsync(d_ws, 0, 4096, stream);

    int dev = 0;
    (void)hipGetDevice(&dev);
    int ncu = 0;
    if (hipDeviceGetAttribute(&ncu, hipDeviceAttributeMultiprocessorCount, dev) != hipSuccess || ncu <= 0)
        ncu = 256;
    int maxB = 0;
    if (hipOccupancyMaxActiveBlocksPerMultiprocessor(&maxB, (const void*)kfused, 256, 0) != hipSuccess || maxB <= 0)
        maxB = 1;
    long cap = (long)maxB * (long)ncu;
    int grd = (cap < 256) ? (int)(cap & ~7L) : 256;
    if (grd < 8) grd = 8;

    for (;;) {
        int nblk = grd >> 3;
        void* args[] = {
            (void*)&lengths, (void*)&eps, (void*)&W_ih, (void*)&b_ih, (void*)&b_hh,
            (void*)&W1a, (void*)&b1a, (void*)&W1b, (void*)&b1b,
            (void*)&W2a, (void*)&b2a, (void*)&W2b, (void*)&b2b,
            (void*)&out_p1, (void*)&out_p2, (void*)&out_h,
            (void*)&bar, (void*)&xT, (void*)&hT, (void*)&haT, (void*)&nblk
        };
        hipError_t err = hipLaunchCooperativeKernel((void*)kfused, dim3(grd), dim3(256), args, 0, stream);
        if (err == hipSuccess || grd <= 8) break;
        grd = (grd >> 1) & ~7;
        if (grd < 8) grd = 8;
    }
}